// Round 10
// baseline (304.847 us; speedup 1.0000x reference)
//
#include <hip/hip_runtime.h>

// NEAT batched forward — one genome per WAVE, zero block barriers.
// R3/R6/R9 all ~110us with no pipe >20% busy: the 8 __syncthreads per genome
// coupled 4 waves so latency stalls never overlapped. Now each wave owns a
// private LDS slice and syncs only with itself (s_waitcnt lgkmcnt(0) +
// sched_barrier, per guide rule #18). Two-pass wave-local bucketing by target
// layer (keys in 2xu64 regs; exact totals via butterfly reduce; ballot replay
// gives identical positions in pass 2). Buckets are per-layer disjoint ->
// agg needs no re-zeroing. LDS 50.7KB/block -> 3 blocks/CU, 12 independent
// wave-genomes resident.

#define NN    256
#define NE    4096
#define NIN   64
#define NOUT  8
#define NWV   4
#define NT    (64 * NWV)
#define CAP   1728   // total live edges: mean 1536, sd 31 (pure binomial) -> 6.2 sigma

#define WAVE_FENCE() do { \
    asm volatile("s_waitcnt lgkmcnt(0)" ::: "memory"); \
    __builtin_amdgcn_sched_barrier(0); \
} while (0)

__global__ __launch_bounds__(NT) void neat_fwd(
    const float* __restrict__ inputs,          // [B,64]
    const int*   __restrict__ node_layer,      // [B,256]
    const int*   __restrict__ conn_in,         // [B,4096]
    const int*   __restrict__ conn_out,        // [B,4096]
    const float* __restrict__ conn_w,          // [B,4096]
    const unsigned char* __restrict__ conn_en, // [B,4096] bool (layout sniffed)
    float*       __restrict__ out)             // [B,8]
{
    const int t    = threadIdx.x;
    const int wv   = t >> 6;
    const int lane = t & 63;
    const unsigned long long lmlt = (1ull << lane) - 1ull;
    const size_t gi = (size_t)blockIdx.x * NWV + wv;   // one genome per wave

    __shared__ float          s_vals[NWV][NN];
    __shared__ float          s_agg [NWV][NN];
    __shared__ unsigned char  s_nl  [NWV][NN];
    __shared__ float          s_ew  [NWV][CAP];
    __shared__ unsigned short s_ep  [NWV][CAP];   // src | (tgt<<8)

    float*          vals = s_vals[wv];
    float*          agg  = s_agg [wv];
    unsigned char*  nl8  = s_nl  [wv];
    float*          ew   = s_ew  [wv];
    unsigned short* ep   = s_ep  [wv];

    // --- sniff conn_enabled element width (uniform): byte bools vs int32 ---
    const unsigned* en_sniff = (const unsigned*)conn_en;
    bool byte_mode = false;
#pragma unroll
    for (int i = 0; i < 16; ++i) byte_mode |= (en_sniff[i] > 1u);

    // --- init (wave-local; NIN == wave width) ---
    const int* nlrow = node_layer + gi * NN;
    const int nlA = nlrow[lane];
    const int nlB = nlrow[lane + 64];
    const int nlC = nlrow[lane + 128];
    const int nlD = nlrow[lane + 192];
    nl8[lane]       = (unsigned char)nlA;
    nl8[lane + 64]  = (unsigned char)nlB;
    nl8[lane + 128] = (unsigned char)nlC;
    nl8[lane + 192] = (unsigned char)nlD;
    vals[lane]       = inputs[gi * NIN + lane];
    vals[lane + 64]  = 0.0f;
    vals[lane + 128] = 0.0f;
    vals[lane + 192] = 0.0f;
    agg[lane]        = 0.0f;
    agg[lane + 64]   = 0.0f;
    agg[lane + 128]  = 0.0f;
    agg[lane + 192]  = 0.0f;
    WAVE_FENCE();   // nl8/vals/agg visible to this wave's random reads

    const int4*   co4 = (const int4*)(conn_out + gi * NE);
    const int4*   ci4 = (const int4*)(conn_in  + gi * NE);
    const float4* w4  = (const float4*)(conn_w  + gi * NE);
    const uchar4* e8  = (const uchar4*)(conn_en + gi * NE);
    const int4*   e32 = (const int4*)((const int*)conn_en + gi * NE);

    // --- pass 1: keys (2 bits/edge in 2xu64) + per-layer counts ---
    unsigned long long keylo = 0, keyhi = 0;
    int c1 = 0, c2 = 0, c3 = 0;

#define P1BODY(KEYVAR, RR) { \
    const int idx = (RR) * 64 + lane; \
    int4 co = co4[idx]; \
    int ex, ey, ez, eq; \
    if (byte_mode) { uchar4 e = e8[idx]; ex = e.x; ey = e.y; ez = e.z; eq = e.w; } \
    else           { int4  e = e32[idx]; ex = e.x; ey = e.y; ez = e.z; eq = e.w; } \
    unsigned kb = 0; \
    { int k = ex ? (int)nl8[co.x] : 0; kb |= (unsigned)k;      c1 += (k==1); c2 += (k==2); c3 += (k==3); } \
    { int k = ey ? (int)nl8[co.y] : 0; kb |= (unsigned)k << 2; c1 += (k==1); c2 += (k==2); c3 += (k==3); } \
    { int k = ez ? (int)nl8[co.z] : 0; kb |= (unsigned)k << 4; c1 += (k==1); c2 += (k==2); c3 += (k==3); } \
    { int k = eq ? (int)nl8[co.w] : 0; kb |= (unsigned)k << 6; c1 += (k==1); c2 += (k==2); c3 += (k==3); } \
    KEYVAR |= (unsigned long long)kb << (8 * ((RR) & 7)); }

#pragma unroll 4
    for (int r = 0; r < 8; ++r)  P1BODY(keylo, r)
#pragma unroll 4
    for (int r = 8; r < 16; ++r) P1BODY(keyhi, r)
#undef P1BODY

    // --- butterfly reduce: exact per-layer totals on every lane ---
#pragma unroll
    for (int off = 1; off < 64; off <<= 1) {
        c1 += __shfl_xor(c1, off);
        c2 += __shfl_xor(c2, off);
        c3 += __shfl_xor(c3, off);
    }
    const int T1 = __builtin_amdgcn_readfirstlane(c1);
    const int T2 = __builtin_amdgcn_readfirstlane(c2);
    const int T3 = __builtin_amdgcn_readfirstlane(c3);
    const int total = T1 + T2 + T3;

    if (total <= CAP) {
        // --- pass 2: ballot replay -> exact bucketed scatter ---
        int b1 = 0, b2 = T1, b3 = T1 + T2;

#define SLOT(K, CI, CO, W) { \
        unsigned long long B1 = __ballot((K) == 1); \
        unsigned long long B2 = __ballot((K) == 2); \
        unsigned long long B3 = __ballot((K) == 3); \
        if (K) { \
            unsigned long long bk = ((K) == 1) ? B1 : (((K) == 2) ? B2 : B3); \
            int bs = ((K) == 1) ? b1 : (((K) == 2) ? b2 : b3); \
            int pos = bs + (int)__popcll(bk & lmlt); \
            ew[pos] = (W); \
            ep[pos] = (unsigned short)((unsigned)(CI) | ((unsigned)(CO) << 8)); \
        } \
        b1 += (int)__popcll(B1); b2 += (int)__popcll(B2); b3 += (int)__popcll(B3); }

#define P2BODY(KEYVAR, RR) { \
        const int idx = (RR) * 64 + lane; \
        int4 ci = ci4[idx]; float4 wq = w4[idx]; int4 co = co4[idx]; \
        unsigned kb = (unsigned)(KEYVAR >> (8 * ((RR) & 7))) & 0xFFu; \
        { int k = (int)(kb        & 3u); SLOT(k, ci.x, co.x, wq.x) } \
        { int k = (int)((kb >> 2) & 3u); SLOT(k, ci.y, co.y, wq.y) } \
        { int k = (int)((kb >> 4) & 3u); SLOT(k, ci.z, co.z, wq.z) } \
        { int k = (int)((kb >> 6) & 3u); SLOT(k, ci.w, co.w, wq.w) } }

#pragma unroll 4
        for (int r = 0; r < 8; ++r)  P2BODY(keylo, r)
#pragma unroll 4
        for (int r = 8; r < 16; ++r) P2BODY(keyhi, r)
#undef P2BODY
#undef SLOT
        WAVE_FENCE();   // buckets ready (this wave only)

        // --- 3 layer passes over this genome's buckets; no re-zero needed ---
#pragma unroll
        for (int L = 1; L <= 3; ++L) {
            const int sBeg = (L == 1) ? 0       : ((L == 2) ? T1 : T1 + T2);
            const int sEnd = (L == 1) ? T1      : ((L == 2) ? T1 + T2 : total);
            for (int p = sBeg + lane; p < sEnd; p += 64) {
                const unsigned pk = ep[p];
                atomicAdd(&agg[pk >> 8], vals[pk & 0xFFu] * ew[p]);
            }
            WAVE_FENCE();   // adds done before updates read agg
            if (nlA == L) vals[lane]       = tanhf(agg[lane]);
            if (nlB == L) vals[lane + 64]  = tanhf(agg[lane + 64]);
            if (nlC == L) vals[lane + 128] = tanhf(agg[lane + 128]);
            if (nlD == L) vals[lane + 192] = tanhf(agg[lane + 192]);
            WAVE_FENCE();   // updates visible before next pass gathers
        }
    } else {
        // --- fallback (never taken on real data): re-stream edges per layer ---
#pragma unroll
        for (int L = 1; L <= 3; ++L) {
            for (int r = 0; r < 16; ++r) {
                const int idx = r * 64 + lane;
                int4 ci = ci4[idx]; int4 co = co4[idx]; float4 wq = w4[idx];
                int ex, ey, ez, eq;
                if (byte_mode) { uchar4 e = e8[idx]; ex = e.x; ey = e.y; ez = e.z; eq = e.w; }
                else           { int4  e = e32[idx]; ex = e.x; ey = e.y; ez = e.z; eq = e.w; }
                if (ex && (int)nl8[co.x] == L) atomicAdd(&agg[co.x], vals[ci.x] * wq.x);
                if (ey && (int)nl8[co.y] == L) atomicAdd(&agg[co.y], vals[ci.y] * wq.y);
                if (ez && (int)nl8[co.z] == L) atomicAdd(&agg[co.z], vals[ci.z] * wq.z);
                if (eq && (int)nl8[co.w] == L) atomicAdd(&agg[co.w], vals[ci.w] * wq.w);
            }
            WAVE_FENCE();
            if (nlA == L) vals[lane]       = tanhf(agg[lane]);
            if (nlB == L) vals[lane + 64]  = tanhf(agg[lane + 64]);
            if (nlC == L) vals[lane + 128] = tanhf(agg[lane + 128]);
            if (nlD == L) vals[lane + 192] = tanhf(agg[lane + 192]);
            WAVE_FENCE();
        }
    }

    if (lane < NOUT)
        out[gi * NOUT + lane] = vals[NIN + lane];
}

extern "C" void kernel_launch(void* const* d_in, const int* in_sizes, int n_in,
                              void* d_out, int out_size, void* d_ws, size_t ws_size,
                              hipStream_t stream) {
    const float* inputs          = (const float*)d_in[0];
    const int*   node_layer      = (const int*)d_in[1];
    const int*   conn_in         = (const int*)d_in[2];
    const int*   conn_out        = (const int*)d_in[3];
    const float* conn_w          = (const float*)d_in[4];
    const unsigned char* conn_en = (const unsigned char*)d_in[5];
    float* out = (float*)d_out;

    const int B = in_sizes[0] / NIN;   // 4096
    neat_fwd<<<B / NWV, NT, 0, stream>>>(inputs, node_layer, conn_in, conn_out,
                                         conn_w, conn_en, out);
}